// Round 3
// baseline (1002.324 us; speedup 1.0000x reference)
//
#include <hip/hip_runtime.h>

// Problem constants (fixed by the reference's setup_inputs)
constexpr int BLK = 256;
constexpr float D_MIN = 0.0f, D_MAX = 20.0f;
constexpr int NUM_RBF = 16;
constexpr float EPS = 1e-8f;
constexpr int NREP = 32;            // accumulator replicas (atomic-contention spread)

// Fixed-point scale for deterministic scatter-add: 2^30
constexpr double FP_SCALE = 1073741824.0;
constexpr double FP_INV = 1.0 / 1073741824.0;

// ---------------------------------------------------------------------------
// Phase 1: scatter-add trans[f_src] onto tfn nodes (int64 fixed point = exact,
// deterministic under atomic reordering) + counts. 32-way replicated
// accumulators cut same-address contention from ~80x to ~2.5x.
// ---------------------------------------------------------------------------
__global__ __launch_bounds__(BLK) void scatter_kernel(
    const float* __restrict__ trans,
    const int* __restrict__ f2t,   // [2, E]: row0 = f_src, row1 = t_dst
    long long* __restrict__ sums,  // [NREP, n_tfn, 3]
    int* __restrict__ cnt,         // [NREP, n_tfn]
    int E, int n_tfn)
{
    int e = blockIdx.x * BLK + threadIdx.x;
    if (e >= E) return;
    int rep = blockIdx.x & (NREP - 1);
    int src = f2t[e];
    int dst = f2t[e + E];
    float x = trans[src * 3 + 0];
    float y = trans[src * 3 + 1];
    float z = trans[src * 3 + 2];
    unsigned long long* s =
        (unsigned long long*)(sums + ((size_t)rep * n_tfn + dst) * 3);
    atomicAdd(s + 0, (unsigned long long)llrint((double)x * FP_SCALE));
    atomicAdd(s + 1, (unsigned long long)llrint((double)y * FP_SCALE));
    atomicAdd(s + 2, (unsigned long long)llrint((double)z * FP_SCALE));
    atomicAdd(cnt + rep * n_tfn + dst, 1);
}

// ---------------------------------------------------------------------------
// Phase 2: reduce replicas (exact int64 adds), tfn_x = sums / max(cnt, 1).
// Float conversion order identical to the previously passing version.
// ---------------------------------------------------------------------------
__global__ __launch_bounds__(BLK) void finalize_kernel(
    const long long* __restrict__ sums,
    const int* __restrict__ cnt,
    float* __restrict__ tfn_x,
    int n_tfn)
{
    int i = blockIdx.x * BLK + threadIdx.x;
    if (i >= n_tfn) return;
    long long sx = 0, sy = 0, sz = 0;
    int c = 0;
    #pragma unroll 4
    for (int r = 0; r < NREP; ++r) {
        const long long* p = sums + ((size_t)r * n_tfn + i) * 3;
        sx += p[0]; sy += p[1]; sz += p[2];
        c += cnt[r * n_tfn + i];
    }
    float fc = fmaxf((float)c, 1.0f);
    tfn_x[i * 3 + 0] = (float)((double)sx * FP_INV) / fc;
    tfn_x[i * 3 + 1] = (float)((double)sy * FP_INV) / fc;
    tfn_x[i * 3 + 2] = (float)((double)sz * FP_INV) / fc;
}

// ---------------------------------------------------------------------------
// Phase 3: per-edge RBF(16) + SH l=0..2 (9) features for all 3 edge types.
// grid.y = edge type. LDS-staged so global stores are fully coalesced float4.
// ---------------------------------------------------------------------------
__global__ __launch_bounds__(BLK) void edge_feats_kernel(
    const float* __restrict__ trans,
    const float* __restrict__ tfn_x,
    const int* __restrict__ f2t,
    const int* __restrict__ t2t,
    const int* __restrict__ t2f,
    float* __restrict__ out,   // [3, E, 25]
    int E)
{
    __shared__ float smem[BLK * 25];

    const int typ = blockIdx.y;
    const int e0 = blockIdx.x * BLK;
    const int e = e0 + threadIdx.x;

    if (e < E) {
        // typ0: trans[f_src] - tfn_x[t_dst]
        // typ1: tfn_x[src]   - tfn_x[dst]
        // typ2: tfn_x[src]   - trans[dst]
        const int* idx = (typ == 0) ? f2t : (typ == 1) ? t2t : t2f;
        const float* abase = (typ == 0) ? trans : tfn_x;
        const float* bbase = (typ == 2) ? trans : tfn_x;
        int i0 = idx[e], i1 = idx[e + E];
        float ax = abase[i0 * 3 + 0], ay = abase[i0 * 3 + 1], az = abase[i0 * 3 + 2];
        float bx = bbase[i1 * 3 + 0], by = bbase[i1 * 3 + 1], bz = bbase[i1 * 3 + 2];

        float vx = ax - bx, vy = ay - by, vz = az - bz;

        // d = || vec + eps ||  (eps added per-component, as in reference)
        float dx = vx + EPS, dy = vy + EPS, dz = vz + EPS;
        float d = sqrtf(dx * dx + dy * dy + dz * dz);

        float* row = smem + threadIdx.x * 25;

        // RBF: mu_i = i * (20/15) (linspace step), sigma = 20/16 -> 1/sigma = 0.8
        constexpr float MU_STEP = (D_MAX - D_MIN) / (NUM_RBF - 1);
        #pragma unroll
        for (int i = 0; i < NUM_RBF; ++i) {
            float t = (d - (float)i * MU_STEP) * 0.8f;
            row[i] = __expf(-(t * t));
        }

        // SH on r = vec / d (original vec, eps-shifted norm)
        float inv_d = 1.0f / d;
        float rx = vx * inv_d, ry = vy * inv_d, rz = vz * inv_d;
        const float s3 = 1.7320508075688772f;
        const float s5 = 2.23606797749979f;
        const float s15 = 3.872983346207417f;
        row[16] = 1.0f;
        row[17] = s3 * rx;
        row[18] = s3 * ry;
        row[19] = s3 * rz;
        row[20] = s15 * rx * ry;
        row[21] = s15 * ry * rz;
        row[22] = 0.5f * s5 * (3.0f * rz * rz - 1.0f);
        row[23] = s15 * rx * rz;
        row[24] = 0.5f * s15 * (rx * rx - ry * ry);
    }
    __syncthreads();

    // Coalesced block-wide store of [cnt_e, 25] floats.
    const int cnt_e = min(BLK, E - e0);
    const int total = cnt_e * 25;
    const size_t base = ((size_t)typ * E + e0) * 25;
    // base*4 bytes is 16B-aligned: typ*E*25*4 = typ*2e8, e0*100 with e0 % 256 == 0.
    float4* out4 = (float4*)(out + base);
    const float4* s4 = (const float4*)smem;
    const int total4 = total >> 2;
    for (int i = threadIdx.x; i < total4; i += BLK) out4[i] = s4[i];
    for (int i = (total4 << 2) + threadIdx.x; i < total; i += BLK) out[base + i] = smem[i];
}

// ---------------------------------------------------------------------------
// Launch
// ---------------------------------------------------------------------------
extern "C" void kernel_launch(void* const* d_in, const int* in_sizes, int n_in,
                              void* d_out, int out_size, void* d_ws, size_t ws_size,
                              hipStream_t stream) {
    const float* trans = (const float*)d_in[0];
    const int* f2t = (const int*)d_in[1];
    const int* t2t = (const int*)d_in[2];
    const int* t2f = (const int*)d_in[3];
    const int n_tfn = 25000;
    const int E = in_sizes[1] / 2;  // 2,000,000

    float* out = (float*)d_out;

    // ws layout: [sums: NREP*n_tfn*3*8 B][cnt: NREP*n_tfn*4 B][tfn_x: n_tfn*3*4 B]
    const size_t sums_bytes = (size_t)NREP * n_tfn * 3 * 8;   // 19.2 MB
    const size_t cnt_bytes  = (size_t)NREP * n_tfn * 4;       //  3.2 MB
    long long* sums = (long long*)d_ws;
    int* cnt = (int*)((char*)d_ws + sums_bytes);
    float* tfn_x = (float*)((char*)d_ws + sums_bytes + cnt_bytes);

    // Zero accumulators (ws is poisoned to 0xAA before every timed launch).
    hipMemsetAsync(d_ws, 0, sums_bytes + cnt_bytes, stream);

    const int nblk_e = (E + BLK - 1) / BLK;
    scatter_kernel<<<nblk_e, BLK, 0, stream>>>(trans, f2t, sums, cnt, E, n_tfn);
    finalize_kernel<<<(n_tfn + BLK - 1) / BLK, BLK, 0, stream>>>(sums, cnt, tfn_x, n_tfn);

    dim3 grid(nblk_e, 3);
    edge_feats_kernel<<<grid, BLK, 0, stream>>>(trans, tfn_x, f2t, t2t, t2f, out, E);
}

// Round 10
// 998.665 us; speedup vs baseline: 1.0037x; 1.0037x over previous
//
#include <hip/hip_runtime.h>

// Problem constants (fixed by the reference's setup_inputs)
constexpr int BLK = 256;
constexpr float D_MIN = 0.0f, D_MAX = 20.0f;
constexpr int NUM_RBF = 16;
constexpr float EPS = 1e-8f;
constexpr int NREP = 32;            // accumulator replicas (atomic-contention spread)

// Fixed-point scale for deterministic scatter-add: 2^30
constexpr double FP_SCALE = 1073741824.0;
constexpr double FP_INV = 1.0 / 1073741824.0;

// exp(-(0.8*(d-mu))^2) == 2^(-(C*(d-mu))^2), C = 0.8*sqrt(log2(e)) = 0.96089794
constexpr float RBF_C = 0.96089794f;

// Native vector type for nontemporal 16B stores (__builtin_nontemporal_store
// rejects HIP_vector_type<float,4>; it needs a real clang ext_vector_type).
typedef float f32x4 __attribute__((ext_vector_type(4)));

// ---------------------------------------------------------------------------
// Phase 1: scatter-add trans[f_src] onto tfn nodes (int64 fixed point = exact,
// deterministic under atomic reordering) + counts. 32-way replicated
// accumulators. float4 gather of trans (rows used < 25000 of 100000, so the
// 16B read at a 12B-stride row never runs past the buffer end).
// ---------------------------------------------------------------------------
__global__ __launch_bounds__(BLK) void scatter_kernel(
    const float* __restrict__ trans,
    const int* __restrict__ f2t,   // [2, E]: row0 = f_src, row1 = t_dst
    long long* __restrict__ sums,  // [NREP, n_tfn, 3]
    int* __restrict__ cnt,         // [NREP, n_tfn]
    int E, int n_tfn)
{
    int e = blockIdx.x * BLK + threadIdx.x;
    if (e >= E) return;
    int rep = blockIdx.x & (NREP - 1);
    int src = f2t[e];
    int dst = f2t[e + E];
    float4 v = *(const float4*)(trans + (size_t)src * 3);
    unsigned long long* s =
        (unsigned long long*)(sums + ((size_t)rep * n_tfn + dst) * 3);
    atomicAdd(s + 0, (unsigned long long)llrint((double)v.x * FP_SCALE));
    atomicAdd(s + 1, (unsigned long long)llrint((double)v.y * FP_SCALE));
    atomicAdd(s + 2, (unsigned long long)llrint((double)v.z * FP_SCALE));
    atomicAdd(cnt + rep * n_tfn + dst, 1);
}

// ---------------------------------------------------------------------------
// Phase 2: reduce replicas (exact int64 adds), tfn_x4 = sums / max(cnt, 1),
// written PADDED [n_tfn][4] so edge-kernel gathers are one dwordx4.
// ---------------------------------------------------------------------------
__global__ __launch_bounds__(BLK) void finalize_kernel(
    const long long* __restrict__ sums,
    const int* __restrict__ cnt,
    float4* __restrict__ tfn_x4,
    int n_tfn)
{
    int i = blockIdx.x * BLK + threadIdx.x;
    if (i >= n_tfn) return;
    long long sx = 0, sy = 0, sz = 0;
    int c = 0;
    #pragma unroll 4
    for (int r = 0; r < NREP; ++r) {
        const long long* p = sums + ((size_t)r * n_tfn + i) * 3;
        sx += p[0]; sy += p[1]; sz += p[2];
        c += cnt[r * n_tfn + i];
    }
    float fc = fmaxf((float)c, 1.0f);
    float4 o;
    o.x = (float)((double)sx * FP_INV) / fc;
    o.y = (float)((double)sy * FP_INV) / fc;
    o.z = (float)((double)sz * FP_INV) / fc;
    o.w = 0.0f;
    tfn_x4[i] = o;
}

// ---------------------------------------------------------------------------
// Phase 3: per-edge RBF(16) + SH l=0..2 (9) features for all 3 edge types.
// grid.y = edge type. LDS-staged; nontemporal coalesced 16B stores.
// ---------------------------------------------------------------------------
__global__ __launch_bounds__(BLK) void edge_feats_kernel(
    const float* __restrict__ trans,
    const float4* __restrict__ tfn_x4,
    const int* __restrict__ f2t,
    const int* __restrict__ t2t,
    const int* __restrict__ t2f,
    float* __restrict__ out,   // [3, E, 25]
    int E)
{
    __shared__ float smem[BLK * 25];

    const int typ = blockIdx.y;
    const int e0 = blockIdx.x * BLK;
    const int e = e0 + threadIdx.x;

    if (e < E) {
        // typ0: trans[f_src] - tfn_x[t_dst]
        // typ1: tfn_x[src]   - tfn_x[dst]
        // typ2: tfn_x[src]   - trans[dst]
        const int* idx = (typ == 0) ? f2t : (typ == 1) ? t2t : t2f;
        int i0 = idx[e], i1 = idx[e + E];

        float4 a = (typ == 0) ? *(const float4*)(trans + (size_t)i0 * 3)
                              : tfn_x4[i0];
        float4 b = (typ == 2) ? *(const float4*)(trans + (size_t)i1 * 3)
                              : tfn_x4[i1];

        float vx = a.x - b.x, vy = a.y - b.y, vz = a.z - b.z;

        // d = || vec + eps ||  (eps added per-component, as in reference)
        float dx = vx + EPS, dy = vy + EPS, dz = vz + EPS;
        float s = dx * dx + dy * dy + dz * dz;
        float inv_d = __builtin_amdgcn_rsqf(s);   // v_rsq_f32
        float d = s * inv_d;                       // sqrt(s)

        float* row = smem + threadIdx.x * 25;

        // RBF: mu_i = i * (20/15) (linspace step); native 2^x transcendental
        constexpr float MU_STEP = (D_MAX - D_MIN) / (NUM_RBF - 1);
        #pragma unroll
        for (int i = 0; i < NUM_RBF; ++i) {
            float t = (d - (float)i * MU_STEP) * RBF_C;
            row[i] = __builtin_amdgcn_exp2f(-(t * t));  // v_exp_f32
        }

        // SH on r = vec / d (original vec, eps-shifted norm)
        float rx = vx * inv_d, ry = vy * inv_d, rz = vz * inv_d;
        const float s3 = 1.7320508075688772f;
        const float s5 = 2.23606797749979f;
        const float s15 = 3.872983346207417f;
        row[16] = 1.0f;
        row[17] = s3 * rx;
        row[18] = s3 * ry;
        row[19] = s3 * rz;
        row[20] = s15 * rx * ry;
        row[21] = s15 * ry * rz;
        row[22] = 0.5f * s5 * (3.0f * rz * rz - 1.0f);
        row[23] = s15 * rx * rz;
        row[24] = 0.5f * s15 * (rx * rx - ry * ry);
    }
    __syncthreads();

    // Coalesced block-wide nontemporal store of [cnt_e, 25] floats.
    const int cnt_e = min(BLK, E - e0);
    const int total = cnt_e * 25;
    const size_t base = ((size_t)typ * E + e0) * 25;
    // base*4 bytes is 16B-aligned: typ*E*25*4 = typ*2e8, e0*100 with e0 % 256 == 0.
    f32x4* out4 = (f32x4*)(out + base);
    const f32x4* s4 = (const f32x4*)smem;
    const int total4 = total >> 2;
    for (int i = threadIdx.x; i < total4; i += BLK)
        __builtin_nontemporal_store(s4[i], out4 + i);
    for (int i = (total4 << 2) + threadIdx.x; i < total; i += BLK)
        __builtin_nontemporal_store(smem[i], out + base + i);
}

// ---------------------------------------------------------------------------
// Launch
// ---------------------------------------------------------------------------
extern "C" void kernel_launch(void* const* d_in, const int* in_sizes, int n_in,
                              void* d_out, int out_size, void* d_ws, size_t ws_size,
                              hipStream_t stream) {
    const float* trans = (const float*)d_in[0];
    const int* f2t = (const int*)d_in[1];
    const int* t2t = (const int*)d_in[2];
    const int* t2f = (const int*)d_in[3];
    const int n_tfn = 25000;
    const int E = in_sizes[1] / 2;  // 2,000,000

    float* out = (float*)d_out;

    // ws layout: [sums: NREP*n_tfn*3*8][cnt: NREP*n_tfn*4][tfn_x4: n_tfn*16]
    const size_t sums_bytes = (size_t)NREP * n_tfn * 3 * 8;   // 19.2 MB
    const size_t cnt_bytes  = (size_t)NREP * n_tfn * 4;       //  3.2 MB
    long long* sums = (long long*)d_ws;
    int* cnt = (int*)((char*)d_ws + sums_bytes);
    float4* tfn_x4 = (float4*)((char*)d_ws + sums_bytes + cnt_bytes);

    // Zero accumulators (ws is poisoned to 0xAA before every timed launch).
    (void)hipMemsetAsync(d_ws, 0, sums_bytes + cnt_bytes, stream);

    const int nblk_e = (E + BLK - 1) / BLK;
    scatter_kernel<<<nblk_e, BLK, 0, stream>>>(trans, f2t, sums, cnt, E, n_tfn);
    finalize_kernel<<<(n_tfn + BLK - 1) / BLK, BLK, 0, stream>>>(sums, cnt, tfn_x4, n_tfn);

    dim3 grid(nblk_e, 3);
    edge_feats_kernel<<<grid, BLK, 0, stream>>>(trans, tfn_x4, f2t, t2t, t2f, out, E);
}